// Round 1
// baseline (408.385 us; speedup 1.0000x reference)
//
#include <hip/hip_runtime.h>
#include <math.h>

#define BB 16
#define QQ 1024
#define TT 1024
#define DD 256
#define EPS 0.1f
#define INV_EPS 10.0f
#define SINK_ITERS 5

// ---------------- row norms: x2[b,q] = sum_d preds^2, y2[b,t] = sum_d targets^2 ----------------
__global__ __launch_bounds__(64) void norms_kernel(
    const float* __restrict__ preds, const float* __restrict__ targets,
    float* __restrict__ x2, float* __restrict__ y2)
{
  int row = blockIdx.x;
  const float* src;
  float* dst;
  if (row < BB*QQ) { src = preds + (size_t)row * DD; dst = x2 + row; }
  else { int r = row - BB*QQ; src = targets + (size_t)r * DD; dst = y2 + r; }
  // D=256 floats = 64 lanes x float4
  float4 v = ((const float4*)src)[threadIdx.x];
  float s = v.x*v.x + v.y*v.y + v.z*v.z + v.w*v.w;
  #pragma unroll
  for (int o = 32; o; o >>= 1) s += __shfl_down(s, o, 64);
  if (threadIdx.x == 0) *dst = s;
}

// ---------------- cost kernel: 64x64 tile / block, 4x4 per thread, fp32 SGEMM-like ----------------
__global__ __launch_bounds__(256) void cost_kernel(
    const float* __restrict__ preds, const float* __restrict__ targets,
    const float* __restrict__ x2, const float* __restrict__ y2,
    float* __restrict__ cost, float* __restrict__ costT, int useT,
    unsigned int* __restrict__ gmax)
{
  __shared__ float As[16][64];
  __shared__ float Bs[16][64];
  __shared__ float sm[4];
  int b  = blockIdx.z;
  int q0 = blockIdx.y * 64;
  int t0 = blockIdx.x * 64;
  const float* Ab = preds   + ((size_t)b*QQ + q0) * DD;
  const float* Bb = targets + ((size_t)b*TT + t0) * DD;
  int tid = threadIdx.x;
  int lr = tid >> 2;           // 0..63: row within tile for staging loads
  int lk = (tid & 3) << 2;     // 0,4,8,12: k offset for float4 load
  int tx = tid & 15, ty = tid >> 4;
  float acc[4][4] = {{0.f}};
  for (int k0 = 0; k0 < DD; k0 += 16) {
    float4 av = *(const float4*)(Ab + (size_t)lr*DD + k0 + lk);
    float4 bv = *(const float4*)(Bb + (size_t)lr*DD + k0 + lk);
    __syncthreads();
    As[lk+0][lr] = av.x; As[lk+1][lr] = av.y; As[lk+2][lr] = av.z; As[lk+3][lr] = av.w;
    Bs[lk+0][lr] = bv.x; Bs[lk+1][lr] = bv.y; Bs[lk+2][lr] = bv.z; Bs[lk+3][lr] = bv.w;
    __syncthreads();
    #pragma unroll
    for (int k = 0; k < 16; ++k) {
      float4 a4 = *(const float4*)&As[k][ty << 2];
      float4 b4 = *(const float4*)&Bs[k][tx << 2];
      float aa[4] = {a4.x, a4.y, a4.z, a4.w};
      float bb[4] = {b4.x, b4.y, b4.z, b4.w};
      #pragma unroll
      for (int i = 0; i < 4; ++i)
        #pragma unroll
        for (int j = 0; j < 4; ++j)
          acc[i][j] = fmaf(aa[i], bb[j], acc[i][j]);
    }
  }
  float xq[4], yt[4];
  #pragma unroll
  for (int i = 0; i < 4; ++i) xq[i] = x2[(size_t)b*QQ + q0 + (ty<<2) + i];
  #pragma unroll
  for (int j = 0; j < 4; ++j) yt[j] = y2[(size_t)b*TT + t0 + (tx<<2) + j];
  float cv[4][4];
  float cm = 0.f;
  #pragma unroll
  for (int i = 0; i < 4; ++i)
    #pragma unroll
    for (int j = 0; j < 4; ++j) {
      float c2 = xq[i] + yt[j] - 2.f*acc[i][j];
      float c = sqrtf(fmaxf(c2, 0.f));
      cv[i][j] = c;
      cm = fmaxf(cm, c);
    }
  #pragma unroll
  for (int i = 0; i < 4; ++i) {
    float4 w = make_float4(cv[i][0], cv[i][1], cv[i][2], cv[i][3]);
    *(float4*)(cost + ((size_t)b*QQ + q0 + (ty<<2) + i) * TT + t0 + (tx<<2)) = w;
  }
  if (useT) {
    #pragma unroll
    for (int j = 0; j < 4; ++j) {
      float4 w = make_float4(cv[0][j], cv[1][j], cv[2][j], cv[3][j]);
      *(float4*)(costT + ((size_t)b*TT + t0 + (tx<<2) + j) * QQ + q0 + (ty<<2)) = w;
    }
  }
  // block max -> one atomic (cost >= 0 so uint bit order == float order)
  #pragma unroll
  for (int o = 32; o; o >>= 1) cm = fmaxf(cm, __shfl_down(cm, o, 64));
  if ((tid & 63) == 0) sm[tid >> 6] = cm;
  __syncthreads();
  if (tid == 0) {
    float m = fmaxf(fmaxf(sm[0], sm[1]), fmaxf(sm[2], sm[3]));
    atomicMax(gmax, __float_as_uint(m));
  }
}

// ---------------- block reduction helpers (256 threads = 4 waves) ----------------
__device__ __forceinline__ float block_max256(float v, float* sm) {
  #pragma unroll
  for (int o = 32; o; o >>= 1) v = fmaxf(v, __shfl_down(v, o, 64));
  if ((threadIdx.x & 63) == 0) sm[threadIdx.x >> 6] = v;
  __syncthreads();
  float r = fmaxf(fmaxf(sm[0], sm[1]), fmaxf(sm[2], sm[3]));
  __syncthreads();
  return r;
}
__device__ __forceinline__ float block_sum256(float v, float* sm) {
  #pragma unroll
  for (int o = 32; o; o >>= 1) v += __shfl_down(v, o, 64);
  if ((threadIdx.x & 63) == 0) sm[threadIdx.x >> 6] = v;
  __syncthreads();
  float r = sm[0] + sm[1] + sm[2] + sm[3];
  __syncthreads();
  return r;
}

// ---------------- u update: u[b,q] = -eps*logsumexp_t((v - cost')/eps) ----------------
__global__ __launch_bounds__(256) void u_kernel(
    const float* __restrict__ cost, const float* __restrict__ filter,
    const float* __restrict__ v, float* __restrict__ u,
    const unsigned int* __restrict__ gmax)
{
  __shared__ float sm[4];
  int row = blockIdx.x;            // b*Q + q
  int b = row >> 10;
  const float* cr = cost + (size_t)row * TT;
  const float* fb = filter + (size_t)b * TT;
  const float* vb = v + (size_t)b * TT;
  float FC = 2.f * __uint_as_float(*gmax);
  float s[4], m = -3.0e38f;
  #pragma unroll
  for (int i = 0; i < 4; ++i) {
    int t = threadIdx.x + (i << 8);
    float c = cr[t];
    if (fb[t] <= 0.f) c = FC;
    s[i] = (vb[t] - c) * INV_EPS;
    m = fmaxf(m, s[i]);
  }
  m = block_max256(m, sm);
  float sum = 0.f;
  #pragma unroll
  for (int i = 0; i < 4; ++i) sum += expf(s[i] - m);
  sum = block_sum256(sum, sm);
  if (threadIdx.x == 0) u[row] = -EPS * (m + logf(sum));
}

// ---------------- v update: v[b,t] = -eps*logsumexp_q((u - cost')/eps) ----------------
__global__ __launch_bounds__(256) void v_kernel(
    const float* __restrict__ cost, const float* __restrict__ costT, int useT,
    const float* __restrict__ filter, const float* __restrict__ u,
    float* __restrict__ v, const unsigned int* __restrict__ gmax)
{
  __shared__ float sm[4];
  int row = blockIdx.x;            // b*T + t
  int b = row >> 10;
  int t = row & 1023;
  const float* ub = u + (size_t)b * QQ;
  float FC = 2.f * __uint_as_float(*gmax);
  bool filt = (filter[row] <= 0.f);
  float s[4], m = -3.0e38f;
  if (filt) {
    // whole column is the constant FC -> no cost reads needed
    #pragma unroll
    for (int i = 0; i < 4; ++i) {
      int q = threadIdx.x + (i << 8);
      s[i] = (ub[q] - FC) * INV_EPS;
      m = fmaxf(m, s[i]);
    }
  } else if (useT) {
    const float* cr = costT + (size_t)row * QQ;
    #pragma unroll
    for (int i = 0; i < 4; ++i) {
      int q = threadIdx.x + (i << 8);
      s[i] = (ub[q] - cr[q]) * INV_EPS;
      m = fmaxf(m, s[i]);
    }
  } else {
    const float* cr = cost + (size_t)b*QQ*TT + t;   // strided fallback (L3-resident)
    #pragma unroll
    for (int i = 0; i < 4; ++i) {
      int q = threadIdx.x + (i << 8);
      s[i] = (ub[q] - cr[(size_t)q * TT]) * INV_EPS;
      m = fmaxf(m, s[i]);
    }
  }
  m = block_max256(m, sm);
  float sum = 0.f;
  #pragma unroll
  for (int i = 0; i < 4; ++i) sum += expf(s[i] - m);
  sum = block_sum256(sum, sm);
  if (threadIdx.x == 0) v[row] = -EPS * (m + logf(sum));
}

// ---------------- final: P = exp((u+v-cost')/eps) in-place, argmax_t -> idx (as float) ----------------
__global__ __launch_bounds__(256) void p_kernel(
    float* __restrict__ P, const float* __restrict__ filter,
    const float* __restrict__ u, const float* __restrict__ v,
    const unsigned int* __restrict__ gmax, float* __restrict__ idxOut)
{
  __shared__ float smp[4];
  __shared__ int smt[4];
  int row = blockIdx.x;            // b*Q + q
  int b = row >> 10;
  float* cr = P + (size_t)row * TT;
  const float* fb = filter + (size_t)b * TT;
  const float* vb = v + (size_t)b * TT;
  float uu = u[row];
  float FC = 2.f * __uint_as_float(*gmax);
  float bestp = -1.f; int bestt = 0;
  float pv[4];
  #pragma unroll
  for (int i = 0; i < 4; ++i) {
    int t = threadIdx.x + (i << 8);
    float c = cr[t];
    if (fb[t] <= 0.f) c = FC;
    float p = expf((uu + vb[t] - c) * INV_EPS);
    pv[i] = p;
    if (p > bestp) { bestp = p; bestt = t; }   // strict > keeps first occurrence
  }
  #pragma unroll
  for (int i = 0; i < 4; ++i) cr[threadIdx.x + (i << 8)] = pv[i];
  #pragma unroll
  for (int o = 32; o; o >>= 1) {
    float op = __shfl_down(bestp, o, 64);
    int   ot = __shfl_down(bestt, o, 64);
    if (op > bestp || (op == bestp && ot < bestt)) { bestp = op; bestt = ot; }
  }
  if ((threadIdx.x & 63) == 0) { smp[threadIdx.x >> 6] = bestp; smt[threadIdx.x >> 6] = bestt; }
  __syncthreads();
  if (threadIdx.x == 0) {
    #pragma unroll
    for (int w = 1; w < 4; ++w)
      if (smp[w] > bestp || (smp[w] == bestp && smt[w] < bestt)) { bestp = smp[w]; bestt = smt[w]; }
    idxOut[row] = (float)bestt;
  }
}

extern "C" void kernel_launch(void* const* d_in, const int* in_sizes, int n_in,
                              void* d_out, int out_size, void* d_ws, size_t ws_size,
                              hipStream_t stream) {
  const float* preds   = (const float*)d_in[0];
  const float* targets = (const float*)d_in[1];
  const float* filter  = (const float*)d_in[2];
  float* out = (float*)d_out;
  float* idxOut = out;                       // output 0: [B,Q] indices (as float)
  float* P = out + (size_t)BB*QQ;            // output 1: [B,Q,T]; cost lives here until p_kernel

  size_t costT_bytes = (size_t)BB * TT * QQ * sizeof(float);
  size_t small_bytes = (size_t)(2*BB*QQ + 2*BB*TT) * sizeof(float) + 256;
  int useT = (ws_size >= costT_bytes + small_bytes) ? 1 : 0;
  char* wsp = (char*)d_ws;
  float* costT = (float*)wsp;
  float* x2 = (float*)(wsp + (useT ? costT_bytes : 0));
  float* y2 = x2 + BB*QQ;
  float* u  = y2 + BB*TT;
  float* v  = u + BB*QQ;
  unsigned int* gmax = (unsigned int*)(v + BB*TT);

  // zero u, v (initial potentials) and gmax (atomicMax accumulator); ws is poisoned 0xAA
  hipMemsetAsync(u, 0, (size_t)(BB*QQ + BB*TT) * sizeof(float) + sizeof(unsigned int), stream);

  norms_kernel<<<BB*(QQ+TT), 64, 0, stream>>>(preds, targets, x2, y2);
  dim3 cg(TT/64, QQ/64, BB);
  cost_kernel<<<cg, 256, 0, stream>>>(preds, targets, x2, y2, P, costT, useT, gmax);
  for (int it = 0; it < SINK_ITERS; ++it) {
    u_kernel<<<BB*QQ, 256, 0, stream>>>(P, filter, v, u, gmax);
    v_kernel<<<BB*TT, 256, 0, stream>>>(P, costT, useT, filter, u, v, gmax);
  }
  p_kernel<<<BB*QQ, 256, 0, stream>>>(P, filter, u, v, gmax, idxOut);
}

// Round 2
// 357.372 us; speedup vs baseline: 1.1427x; 1.1427x over previous
//
#include <hip/hip_runtime.h>
#include <math.h>

#define BB 16
#define QQ 1024
#define TT 1024
#define DD 256
#define EPS 0.1f
#define INV_EPS 10.0f
#define SINK_ITERS 5

#define TILE 128
#define KC 16
#define LDSTR 132   // 128 + 4 pad: staging writes 2-way max (free), 16B-aligned rows

// ---------------- row norms ----------------
__global__ __launch_bounds__(64) void norms_kernel(
    const float* __restrict__ preds, const float* __restrict__ targets,
    float* __restrict__ x2, float* __restrict__ y2)
{
  int row = blockIdx.x;
  const float* src;
  float* dst;
  if (row < BB*QQ) { src = preds + (size_t)row * DD; dst = x2 + row; }
  else { int r = row - BB*QQ; src = targets + (size_t)r * DD; dst = y2 + r; }
  float4 v = ((const float4*)src)[threadIdx.x];
  float s = v.x*v.x + v.y*v.y + v.z*v.z + v.w*v.w;
  #pragma unroll
  for (int o = 32; o; o >>= 1) s += __shfl_down(s, o, 64);
  if (threadIdx.x == 0) *dst = s;
}

// ---------------- cost kernel: 128x128 tile, 8x8 microtile ----------------
__global__ __launch_bounds__(256) void cost_kernel(
    const float* __restrict__ preds, const float* __restrict__ targets,
    const float* __restrict__ x2, const float* __restrict__ y2,
    float* __restrict__ cost, float* __restrict__ costT, int useT,
    unsigned int* __restrict__ gmax)
{
  __shared__ float As[KC*LDSTR];
  __shared__ float Bs[KC*LDSTR];
  __shared__ float sm[4];
  int b  = blockIdx.z;
  int q0 = blockIdx.y * TILE;
  int t0 = blockIdx.x * TILE;
  const float* Ab = preds   + ((size_t)b*QQ + q0) * DD;
  const float* Bb = targets + ((size_t)b*TT + t0) * DD;
  int tid = threadIdx.x;
  // staging: idx in {tid, tid+256}; row = idx>>2 (0..127), k-quad = (idx&3)*4
  int srow = tid >> 2;
  int sq   = (tid & 3) << 2;
  // fragments: wave w owns a 64x64 subtile; lane -> 8x8 microtile
  int w = tid >> 6;
  int l = tid & 63;
  int rq = ((w >> 1) << 6) + ((l >> 3) << 3);  // row offset in tile
  int rt = ((w & 1) << 6) + ((l & 7) << 3);    // col offset in tile
  float acc[8][8] = {};
  for (int k0 = 0; k0 < DD; k0 += KC) {
    float4 a0 = *(const float4*)(Ab + (size_t)srow*DD + k0 + sq);
    float4 a1 = *(const float4*)(Ab + (size_t)(srow+64)*DD + k0 + sq);
    float4 b0 = *(const float4*)(Bb + (size_t)srow*DD + k0 + sq);
    float4 b1 = *(const float4*)(Bb + (size_t)(srow+64)*DD + k0 + sq);
    __syncthreads();
    As[(sq+0)*LDSTR + srow] = a0.x; As[(sq+1)*LDSTR + srow] = a0.y;
    As[(sq+2)*LDSTR + srow] = a0.z; As[(sq+3)*LDSTR + srow] = a0.w;
    As[(sq+0)*LDSTR + srow+64] = a1.x; As[(sq+1)*LDSTR + srow+64] = a1.y;
    As[(sq+2)*LDSTR + srow+64] = a1.z; As[(sq+3)*LDSTR + srow+64] = a1.w;
    Bs[(sq+0)*LDSTR + srow] = b0.x; Bs[(sq+1)*LDSTR + srow] = b0.y;
    Bs[(sq+2)*LDSTR + srow] = b0.z; Bs[(sq+3)*LDSTR + srow] = b0.w;
    Bs[(sq+0)*LDSTR + srow+64] = b1.x; Bs[(sq+1)*LDSTR + srow+64] = b1.y;
    Bs[(sq+2)*LDSTR + srow+64] = b1.z; Bs[(sq+3)*LDSTR + srow+64] = b1.w;
    __syncthreads();
    #pragma unroll
    for (int k = 0; k < KC; ++k) {
      float4 af0 = *(const float4*)&As[k*LDSTR + rq];
      float4 af1 = *(const float4*)&As[k*LDSTR + rq + 4];
      float4 bf0 = *(const float4*)&Bs[k*LDSTR + rt];
      float4 bf1 = *(const float4*)&Bs[k*LDSTR + rt + 4];
      float aa[8] = {af0.x,af0.y,af0.z,af0.w,af1.x,af1.y,af1.z,af1.w};
      float bb[8] = {bf0.x,bf0.y,bf0.z,bf0.w,bf1.x,bf1.y,bf1.z,bf1.w};
      #pragma unroll
      for (int i = 0; i < 8; ++i)
        #pragma unroll
        for (int j = 0; j < 8; ++j)
          acc[i][j] = fmaf(aa[i], bb[j], acc[i][j]);
    }
  }
  float xq[8], yt[8];
  #pragma unroll
  for (int i = 0; i < 8; ++i) xq[i] = x2[(size_t)b*QQ + q0 + rq + i];
  #pragma unroll
  for (int j = 0; j < 8; ++j) yt[j] = y2[(size_t)b*TT + t0 + rt + j];
  float cv[8][8];
  float cm = 0.f;
  #pragma unroll
  for (int i = 0; i < 8; ++i)
    #pragma unroll
    for (int j = 0; j < 8; ++j) {
      float c2 = xq[i] + yt[j] - 2.f*acc[i][j];
      float c = sqrtf(fmaxf(c2, 0.f));
      cv[i][j] = c;
      cm = fmaxf(cm, c);
    }
  #pragma unroll
  for (int i = 0; i < 8; ++i) {
    float* dst = cost + ((size_t)b*QQ + q0 + rq + i) * TT + t0 + rt;
    *(float4*)dst       = make_float4(cv[i][0], cv[i][1], cv[i][2], cv[i][3]);
    *(float4*)(dst + 4) = make_float4(cv[i][4], cv[i][5], cv[i][6], cv[i][7]);
  }
  if (useT) {
    #pragma unroll
    for (int j = 0; j < 8; ++j) {
      float* dst = costT + ((size_t)b*TT + t0 + rt + j) * QQ + q0 + rq;
      *(float4*)dst       = make_float4(cv[0][j], cv[1][j], cv[2][j], cv[3][j]);
      *(float4*)(dst + 4) = make_float4(cv[4][j], cv[5][j], cv[6][j], cv[7][j]);
    }
  }
  #pragma unroll
  for (int o = 32; o; o >>= 1) cm = fmaxf(cm, __shfl_down(cm, o, 64));
  if ((tid & 63) == 0) sm[tid >> 6] = cm;
  __syncthreads();
  if (tid == 0) {
    float m = fmaxf(fmaxf(sm[0], sm[1]), fmaxf(sm[2], sm[3]));
    atomicMax(gmax, __float_as_uint(m));
  }
}

// ---------------- wave reduction helpers (butterfly, all lanes get result) ----------------
__device__ __forceinline__ float wave_max64(float v) {
  #pragma unroll
  for (int o = 1; o < 64; o <<= 1) v = fmaxf(v, __shfl_xor(v, o, 64));
  return v;
}
__device__ __forceinline__ float wave_sum64(float v) {
  #pragma unroll
  for (int o = 1; o < 64; o <<= 1) v += __shfl_xor(v, o, 64);
  return v;
}

// ---------------- u update: one wave per (b,q) row ----------------
__global__ __launch_bounds__(256) void u_kernel(
    const float* __restrict__ cost, const float* __restrict__ filter,
    const float* __restrict__ v, float* __restrict__ u,
    const unsigned int* __restrict__ gmax)
{
  int row = (blockIdx.x << 2) + (threadIdx.x >> 6);  // b*Q + q
  int l = threadIdx.x & 63;
  int b = row >> 10;
  const float4* cr = (const float4*)(cost + (size_t)row * TT);
  const float4* fb = (const float4*)(filter + (size_t)b * TT);
  const float4* vb = (const float4*)(v + (size_t)b * TT);
  float FC = 2.f * __uint_as_float(*gmax);
  float s[16];
  float m = -3.0e38f;
  #pragma unroll
  for (int i = 0; i < 4; ++i) {
    float4 c4 = cr[l + (i << 6)];
    float4 f4 = fb[l + (i << 6)];
    float4 v4 = vb[l + (i << 6)];
    float c0 = (f4.x <= 0.f) ? FC : c4.x;
    float c1 = (f4.y <= 0.f) ? FC : c4.y;
    float c2 = (f4.z <= 0.f) ? FC : c4.z;
    float c3 = (f4.w <= 0.f) ? FC : c4.w;
    s[4*i+0] = (v4.x - c0) * INV_EPS;
    s[4*i+1] = (v4.y - c1) * INV_EPS;
    s[4*i+2] = (v4.z - c2) * INV_EPS;
    s[4*i+3] = (v4.w - c3) * INV_EPS;
    m = fmaxf(m, fmaxf(fmaxf(s[4*i+0], s[4*i+1]), fmaxf(s[4*i+2], s[4*i+3])));
  }
  m = wave_max64(m);
  float sum = 0.f;
  #pragma unroll
  for (int i = 0; i < 16; ++i) sum += expf(s[i] - m);
  sum = wave_sum64(sum);
  if (l == 0) u[row] = -EPS * (m + logf(sum));
}

// ---------------- v update: one wave per (b,t) column ----------------
__global__ __launch_bounds__(256) void v_kernel(
    const float* __restrict__ cost, const float* __restrict__ costT, int useT,
    const float* __restrict__ filter, const float* __restrict__ u,
    float* __restrict__ v, const unsigned int* __restrict__ gmax)
{
  int row = (blockIdx.x << 2) + (threadIdx.x >> 6);  // b*T + t
  int l = threadIdx.x & 63;
  int b = row >> 10;
  int t = row & 1023;
  const float4* ub = (const float4*)(u + (size_t)b * QQ);
  float FC = 2.f * __uint_as_float(*gmax);
  bool filt = (filter[row] <= 0.f);   // wave-uniform
  float s[16];
  float m = -3.0e38f;
  if (filt) {
    #pragma unroll
    for (int i = 0; i < 4; ++i) {
      float4 u4 = ub[l + (i << 6)];
      s[4*i+0] = (u4.x - FC) * INV_EPS;
      s[4*i+1] = (u4.y - FC) * INV_EPS;
      s[4*i+2] = (u4.z - FC) * INV_EPS;
      s[4*i+3] = (u4.w - FC) * INV_EPS;
      m = fmaxf(m, fmaxf(fmaxf(s[4*i+0], s[4*i+1]), fmaxf(s[4*i+2], s[4*i+3])));
    }
  } else if (useT) {
    const float4* cr = (const float4*)(costT + (size_t)row * QQ);
    #pragma unroll
    for (int i = 0; i < 4; ++i) {
      float4 u4 = ub[l + (i << 6)];
      float4 c4 = cr[l + (i << 6)];
      s[4*i+0] = (u4.x - c4.x) * INV_EPS;
      s[4*i+1] = (u4.y - c4.y) * INV_EPS;
      s[4*i+2] = (u4.z - c4.z) * INV_EPS;
      s[4*i+3] = (u4.w - c4.w) * INV_EPS;
      m = fmaxf(m, fmaxf(fmaxf(s[4*i+0], s[4*i+1]), fmaxf(s[4*i+2], s[4*i+3])));
    }
  } else {
    const float* cr = cost + (size_t)b*QQ*TT + t;
    #pragma unroll
    for (int i = 0; i < 4; ++i) {
      float4 u4 = ub[l + (i << 6)];
      int q = (l + (i << 6)) << 2;
      float c0 = cr[(size_t)(q+0) * TT];
      float c1 = cr[(size_t)(q+1) * TT];
      float c2 = cr[(size_t)(q+2) * TT];
      float c3 = cr[(size_t)(q+3) * TT];
      s[4*i+0] = (u4.x - c0) * INV_EPS;
      s[4*i+1] = (u4.y - c1) * INV_EPS;
      s[4*i+2] = (u4.z - c2) * INV_EPS;
      s[4*i+3] = (u4.w - c3) * INV_EPS;
      m = fmaxf(m, fmaxf(fmaxf(s[4*i+0], s[4*i+1]), fmaxf(s[4*i+2], s[4*i+3])));
    }
  }
  m = wave_max64(m);
  float sum = 0.f;
  #pragma unroll
  for (int i = 0; i < 16; ++i) sum += expf(s[i] - m);
  sum = wave_sum64(sum);
  if (l == 0) v[row] = -EPS * (m + logf(sum));
}

// ---------------- final: P in-place over cost, argmax_t -> idx ----------------
__global__ __launch_bounds__(256) void p_kernel(
    float* __restrict__ P, const float* __restrict__ filter,
    const float* __restrict__ u, const float* __restrict__ v,
    const unsigned int* __restrict__ gmax, float* __restrict__ idxOut)
{
  int row = (blockIdx.x << 2) + (threadIdx.x >> 6);  // b*Q + q
  int l = threadIdx.x & 63;
  int b = row >> 10;
  float4* cr = (float4*)(P + (size_t)row * TT);
  const float4* fb = (const float4*)(filter + (size_t)b * TT);
  const float4* vb = (const float4*)(v + (size_t)b * TT);
  float uu = u[row];
  float FC = 2.f * __uint_as_float(*gmax);
  float bestp = -1.f; int bestt = 0;
  #pragma unroll
  for (int i = 0; i < 4; ++i) {
    float4 c4 = cr[l + (i << 6)];
    float4 f4 = fb[l + (i << 6)];
    float4 v4 = vb[l + (i << 6)];
    int t0 = (l + (i << 6)) << 2;
    float c0 = (f4.x <= 0.f) ? FC : c4.x;
    float c1 = (f4.y <= 0.f) ? FC : c4.y;
    float c2 = (f4.z <= 0.f) ? FC : c4.z;
    float c3 = (f4.w <= 0.f) ? FC : c4.w;
    float4 p4;
    p4.x = expf((uu + v4.x - c0) * INV_EPS);
    p4.y = expf((uu + v4.y - c1) * INV_EPS);
    p4.z = expf((uu + v4.z - c2) * INV_EPS);
    p4.w = expf((uu + v4.w - c3) * INV_EPS);
    // ascending t within lane -> strict > keeps first occurrence
    if (p4.x > bestp) { bestp = p4.x; bestt = t0 + 0; }
    if (p4.y > bestp) { bestp = p4.y; bestt = t0 + 1; }
    if (p4.z > bestp) { bestp = p4.z; bestt = t0 + 2; }
    if (p4.w > bestp) { bestp = p4.w; bestt = t0 + 3; }
    cr[l + (i << 6)] = p4;
  }
  #pragma unroll
  for (int o = 1; o < 64; o <<= 1) {
    float op = __shfl_xor(bestp, o, 64);
    int   ot = __shfl_xor(bestt, o, 64);
    if (op > bestp || (op == bestp && ot < bestt)) { bestp = op; bestt = ot; }
  }
  if (l == 0) idxOut[row] = (float)bestt;
}

extern "C" void kernel_launch(void* const* d_in, const int* in_sizes, int n_in,
                              void* d_out, int out_size, void* d_ws, size_t ws_size,
                              hipStream_t stream) {
  const float* preds   = (const float*)d_in[0];
  const float* targets = (const float*)d_in[1];
  const float* filter  = (const float*)d_in[2];
  float* out = (float*)d_out;
  float* idxOut = out;                       // output 0: [B,Q] indices (as float)
  float* P = out + (size_t)BB*QQ;            // output 1: [B,Q,T]; cost lives here until p_kernel

  size_t costT_bytes = (size_t)BB * TT * QQ * sizeof(float);
  size_t small_bytes = (size_t)(2*BB*QQ + 2*BB*TT) * sizeof(float) + 256;
  int useT = (ws_size >= costT_bytes + small_bytes) ? 1 : 0;
  char* wsp = (char*)d_ws;
  float* costT = (float*)wsp;
  float* x2 = (float*)(wsp + (useT ? costT_bytes : 0));
  float* y2 = x2 + BB*QQ;
  float* u  = y2 + BB*TT;
  float* v  = u + BB*QQ;
  unsigned int* gmax = (unsigned int*)(v + BB*TT);

  hipMemsetAsync(u, 0, (size_t)(BB*QQ + BB*TT) * sizeof(float) + sizeof(unsigned int), stream);

  norms_kernel<<<BB*(QQ+TT), 64, 0, stream>>>(preds, targets, x2, y2);
  dim3 cg(TT/TILE, QQ/TILE, BB);
  cost_kernel<<<cg, 256, 0, stream>>>(preds, targets, x2, y2, P, costT, useT, gmax);
  int rows_q = BB*QQ/4, rows_t = BB*TT/4;
  for (int it = 0; it < SINK_ITERS; ++it) {
    u_kernel<<<rows_q, 256, 0, stream>>>(P, filter, v, u, gmax);
    v_kernel<<<rows_t, 256, 0, stream>>>(P, costT, useT, filter, u, v, gmax);
  }
  p_kernel<<<rows_q, 256, 0, stream>>>(P, filter, u, v, gmax, idxOut);
}

// Round 3
// 286.947 us; speedup vs baseline: 1.4232x; 1.2454x over previous
//
#include <hip/hip_runtime.h>
#include <math.h>

#define BB 16
#define QQ 1024
#define TT 1024
#define DD 256
#define EPS 0.1f
#define INV_EPS 10.0f
#define SINK_ITERS 5
// FC replaces 2*max(cost). Mathematically FC cancels everywhere (filtered col:
// v_t = FC - eps*lse(u/eps); every consumer computes v_t - FC), as long as
// FC >> max(cost)+2 so filtered terms vanish in unfiltered lse's. max cost ~40.
#define FCONST 128.0f

typedef _Float16 f16;
typedef _Float16 f16x4 __attribute__((ext_vector_type(4)));
typedef _Float16 f16x8 __attribute__((ext_vector_type(8)));
typedef float f32x4 __attribute__((ext_vector_type(4)));

// ---------------- cvt: fp32 -> (hi,lo) f16 split + fused row norms ----------------
__global__ __launch_bounds__(256) void cvt_kernel(
    const float* __restrict__ preds, const float* __restrict__ targets,
    f16* __restrict__ Ahi, f16* __restrict__ Alo,
    f16* __restrict__ Bhi, f16* __restrict__ Blo,
    float* __restrict__ x2, float* __restrict__ y2)
{
  int w = threadIdx.x >> 6, l = threadIdx.x & 63;
  int row = blockIdx.x * 4 + w;
  const float* src; f16 *hi, *lo; float* nrm;
  if (row < BB*QQ) {
    src = preds + (size_t)row * DD;
    hi = Ahi + (size_t)row * DD; lo = Alo + (size_t)row * DD; nrm = x2 + row;
  } else {
    int r = row - BB*QQ;
    src = targets + (size_t)r * DD;
    hi = Bhi + (size_t)r * DD; lo = Blo + (size_t)r * DD; nrm = y2 + r;
  }
  float4 v = ((const float4*)src)[l];
  f16x4 h, lw;
  h.x = (f16)v.x; h.y = (f16)v.y; h.z = (f16)v.z; h.w = (f16)v.w;
  lw.x = (f16)(v.x - (float)h.x); lw.y = (f16)(v.y - (float)h.y);
  lw.z = (f16)(v.z - (float)h.z); lw.w = (f16)(v.w - (float)h.w);
  *(f16x4*)(hi + l*4) = h;
  *(f16x4*)(lo + l*4) = lw;
  float s = v.x*v.x + v.y*v.y + v.z*v.z + v.w*v.w;
  #pragma unroll
  for (int o = 32; o; o >>= 1) s += __shfl_down(s, o, 64);
  if (l == 0) *nrm = s;
}

// ---------------- MFMA cost kernel: 128x128 tile, 64x64/wave, 16x16x32 f16 ----------------
__global__ __launch_bounds__(256) void cost_mfma_kernel(
    const f16* __restrict__ Ahi, const f16* __restrict__ Alo,
    const f16* __restrict__ Bhi, const f16* __restrict__ Blo,
    const float* __restrict__ x2, const float* __restrict__ y2,
    const float* __restrict__ filter,
    float* __restrict__ cost, float* __restrict__ costT, int useT)
{
  __shared__ f16 sA[2][128*32];   // [hi/lo][row-major 128 rows x 32 k]
  __shared__ f16 sB[2][128*32];
  int b = blockIdx.z;
  int q0 = blockIdx.y * 128, t0 = blockIdx.x * 128;
  int tid = threadIdx.x, w = tid >> 6, l = tid & 63;
  int rq = (w >> 1) * 64, rt = (w & 1) * 64;   // wave's 64x64 subtile
  int fr = l & 15, fg = l >> 4;                // frag row idx, k/row group
  const f16* pA[2] = { Ahi + ((size_t)b*QQ + q0) * DD, Alo + ((size_t)b*QQ + q0) * DD };
  const f16* pB[2] = { Bhi + ((size_t)b*TT + t0) * DD, Blo + ((size_t)b*TT + t0) * DD };
  f32x4 acc[4][4] = {};
  for (int k0 = 0; k0 < DD; k0 += 32) {
    __syncthreads();
#if __has_builtin(__builtin_amdgcn_global_load_lds)
    #pragma unroll
    for (int j = 0; j < 2; ++j) {
      int chunk = w*128 + j*64 + l;         // 16B chunk id: row=chunk>>2, kc=chunk&3
      int row = chunk >> 2, kc = chunk & 3;
      size_t go = (size_t)row * DD + k0 + kc*8;
      int lb = (w*128 + j*64) * 8;          // wave-uniform LDS base (f16 elems)
      #pragma unroll
      for (int h = 0; h < 2; ++h) {
        __builtin_amdgcn_global_load_lds(
            (const __attribute__((address_space(1))) void*)(pA[h] + go),
            (__attribute__((address_space(3))) void*)&sA[h][lb], 16, 0, 0);
        __builtin_amdgcn_global_load_lds(
            (const __attribute__((address_space(1))) void*)(pB[h] + go),
            (__attribute__((address_space(3))) void*)&sB[h][lb], 16, 0, 0);
      }
    }
#else
    #pragma unroll
    for (int j = 0; j < 2; ++j) {
      int chunk = w*128 + j*64 + l;
      int row = chunk >> 2, kc = chunk & 3;
      size_t go = (size_t)row * DD + k0 + kc*8;
      #pragma unroll
      for (int h = 0; h < 2; ++h) {
        *(f16x8*)&sA[h][chunk*8] = *(const f16x8*)(pA[h] + go);
        *(f16x8*)&sB[h][chunk*8] = *(const f16x8*)(pB[h] + go);
      }
    }
#endif
    __syncthreads();
    f16x8 ah[4], al[4], bh[4], bl[4];
    #pragma unroll
    for (int f = 0; f < 4; ++f) {
      int ao = (rq + f*16 + fr)*32 + fg*8;
      ah[f] = *(const f16x8*)&sA[0][ao];
      al[f] = *(const f16x8*)&sA[1][ao];
      int bo = (rt + f*16 + fr)*32 + fg*8;
      bh[f] = *(const f16x8*)&sB[0][bo];
      bl[f] = *(const f16x8*)&sB[1][bo];
    }
    #pragma unroll
    for (int fm = 0; fm < 4; ++fm)
      #pragma unroll
      for (int fn = 0; fn < 4; ++fn) {
        acc[fm][fn] = __builtin_amdgcn_mfma_f32_16x16x32_f16(ah[fm], bh[fn], acc[fm][fn], 0, 0, 0);
        acc[fm][fn] = __builtin_amdgcn_mfma_f32_16x16x32_f16(ah[fm], bl[fn], acc[fm][fn], 0, 0, 0);
        acc[fm][fn] = __builtin_amdgcn_mfma_f32_16x16x32_f16(al[fm], bh[fn], acc[fm][fn], 0, 0, 0);
      }
  }
  // epilogue: C/D layout col=lane&15 (t), row=(lane>>4)*4+reg (q)
  float xv[16];
  #pragma unroll
  for (int fm = 0; fm < 4; ++fm)
    #pragma unroll
    for (int r = 0; r < 4; ++r)
      xv[fm*4+r] = x2[(size_t)b*QQ + q0 + rq + fm*16 + fg*4 + r];
  float yv[4], fv[4];
  #pragma unroll
  for (int fn = 0; fn < 4; ++fn) {
    int t = t0 + rt + fn*16 + fr;
    yv[fn] = y2[(size_t)b*TT + t];
    fv[fn] = filter[(size_t)b*TT + t];
  }
  #pragma unroll
  for (int fm = 0; fm < 4; ++fm) {
    #pragma unroll
    for (int fn = 0; fn < 4; ++fn) {
      int t = t0 + rt + fn*16 + fr;
      float cvr[4];
      #pragma unroll
      for (int r = 0; r < 4; ++r) {
        float c2 = xv[fm*4+r] + yv[fn] - 2.0f*acc[fm][fn][r];
        float c = sqrtf(fmaxf(c2, 0.f));
        if (fv[fn] <= 0.f) c = FCONST;      // bake filter into stored cost
        cvr[r] = c;
        int q = q0 + rq + fm*16 + fg*4 + r;
        cost[((size_t)b*QQ + q)*TT + t] = c;
      }
      if (useT) {
        float* dst = costT + ((size_t)b*TT + t)*QQ + q0 + rq + fm*16 + fg*4;
        *(float4*)dst = make_float4(cvr[0], cvr[1], cvr[2], cvr[3]);
      }
    }
  }
}

// ---------------- fp32 fallback (only if ws too small for f16 arrays) ----------------
__global__ __launch_bounds__(64) void norms_kernel(
    const float* __restrict__ preds, const float* __restrict__ targets,
    float* __restrict__ x2, float* __restrict__ y2)
{
  int row = blockIdx.x;
  const float* src; float* dst;
  if (row < BB*QQ) { src = preds + (size_t)row * DD; dst = x2 + row; }
  else { int r = row - BB*QQ; src = targets + (size_t)r * DD; dst = y2 + r; }
  float4 v = ((const float4*)src)[threadIdx.x];
  float s = v.x*v.x + v.y*v.y + v.z*v.z + v.w*v.w;
  #pragma unroll
  for (int o = 32; o; o >>= 1) s += __shfl_down(s, o, 64);
  if (threadIdx.x == 0) *dst = s;
}

#define LDSTR 132
__global__ __launch_bounds__(256) void cost_fp32_kernel(
    const float* __restrict__ preds, const float* __restrict__ targets,
    const float* __restrict__ x2, const float* __restrict__ y2,
    const float* __restrict__ filter,
    float* __restrict__ cost, float* __restrict__ costT, int useT)
{
  __shared__ float As[16*LDSTR];
  __shared__ float Bs[16*LDSTR];
  int b  = blockIdx.z;
  int q0 = blockIdx.y * 128;
  int t0 = blockIdx.x * 128;
  const float* Ab = preds   + ((size_t)b*QQ + q0) * DD;
  const float* Bb = targets + ((size_t)b*TT + t0) * DD;
  int tid = threadIdx.x;
  int srow = tid >> 2, sq = (tid & 3) << 2;
  int w = tid >> 6, l = tid & 63;
  int rq = ((w >> 1) << 6) + ((l >> 3) << 3);
  int rt = ((w & 1) << 6) + ((l & 7) << 3);
  float acc[8][8] = {};
  for (int k0 = 0; k0 < DD; k0 += 16) {
    float4 a0 = *(const float4*)(Ab + (size_t)srow*DD + k0 + sq);
    float4 a1 = *(const float4*)(Ab + (size_t)(srow+64)*DD + k0 + sq);
    float4 b0 = *(const float4*)(Bb + (size_t)srow*DD + k0 + sq);
    float4 b1 = *(const float4*)(Bb + (size_t)(srow+64)*DD + k0 + sq);
    __syncthreads();
    As[(sq+0)*LDSTR + srow] = a0.x; As[(sq+1)*LDSTR + srow] = a0.y;
    As[(sq+2)*LDSTR + srow] = a0.z; As[(sq+3)*LDSTR + srow] = a0.w;
    As[(sq+0)*LDSTR + srow+64] = a1.x; As[(sq+1)*LDSTR + srow+64] = a1.y;
    As[(sq+2)*LDSTR + srow+64] = a1.z; As[(sq+3)*LDSTR + srow+64] = a1.w;
    Bs[(sq+0)*LDSTR + srow] = b0.x; Bs[(sq+1)*LDSTR + srow] = b0.y;
    Bs[(sq+2)*LDSTR + srow] = b0.z; Bs[(sq+3)*LDSTR + srow] = b0.w;
    Bs[(sq+0)*LDSTR + srow+64] = b1.x; Bs[(sq+1)*LDSTR + srow+64] = b1.y;
    Bs[(sq+2)*LDSTR + srow+64] = b1.z; Bs[(sq+3)*LDSTR + srow+64] = b1.w;
    __syncthreads();
    #pragma unroll
    for (int k = 0; k < 16; ++k) {
      float4 af0 = *(const float4*)&As[k*LDSTR + rq];
      float4 af1 = *(const float4*)&As[k*LDSTR + rq + 4];
      float4 bf0 = *(const float4*)&Bs[k*LDSTR + rt];
      float4 bf1 = *(const float4*)&Bs[k*LDSTR + rt + 4];
      float aa[8] = {af0.x,af0.y,af0.z,af0.w,af1.x,af1.y,af1.z,af1.w};
      float bb[8] = {bf0.x,bf0.y,bf0.z,bf0.w,bf1.x,bf1.y,bf1.z,bf1.w};
      #pragma unroll
      for (int i = 0; i < 8; ++i)
        #pragma unroll
        for (int j = 0; j < 8; ++j)
          acc[i][j] = fmaf(aa[i], bb[j], acc[i][j]);
    }
  }
  float xq[8], yt[8], fvv[8];
  #pragma unroll
  for (int i = 0; i < 8; ++i) xq[i] = x2[(size_t)b*QQ + q0 + rq + i];
  #pragma unroll
  for (int j = 0; j < 8; ++j) {
    yt[j] = y2[(size_t)b*TT + t0 + rt + j];
    fvv[j] = filter[(size_t)b*TT + t0 + rt + j];
  }
  float cv[8][8];
  #pragma unroll
  for (int i = 0; i < 8; ++i)
    #pragma unroll
    for (int j = 0; j < 8; ++j) {
      float c2 = xq[i] + yt[j] - 2.f*acc[i][j];
      float c = sqrtf(fmaxf(c2, 0.f));
      if (fvv[j] <= 0.f) c = FCONST;
      cv[i][j] = c;
    }
  #pragma unroll
  for (int i = 0; i < 8; ++i) {
    float* dst = cost + ((size_t)b*QQ + q0 + rq + i) * TT + t0 + rt;
    *(float4*)dst       = make_float4(cv[i][0], cv[i][1], cv[i][2], cv[i][3]);
    *(float4*)(dst + 4) = make_float4(cv[i][4], cv[i][5], cv[i][6], cv[i][7]);
  }
  if (useT) {
    #pragma unroll
    for (int j = 0; j < 8; ++j) {
      float* dst = costT + ((size_t)b*TT + t0 + rt + j) * QQ + q0 + rq;
      *(float4*)dst       = make_float4(cv[0][j], cv[1][j], cv[2][j], cv[3][j]);
      *(float4*)(dst + 4) = make_float4(cv[4][j], cv[5][j], cv[6][j], cv[7][j]);
    }
  }
}

// ---------------- wave reductions ----------------
__device__ __forceinline__ float wave_max64(float v) {
  #pragma unroll
  for (int o = 1; o < 64; o <<= 1) v = fmaxf(v, __shfl_xor(v, o, 64));
  return v;
}
__device__ __forceinline__ float wave_sum64(float v) {
  #pragma unroll
  for (int o = 1; o < 64; o <<= 1) v += __shfl_xor(v, o, 64);
  return v;
}

// ---------------- u update (filter pre-baked into cost) ----------------
__global__ __launch_bounds__(256) void u_kernel(
    const float* __restrict__ cost, const float* __restrict__ v, float* __restrict__ u)
{
  int row = (blockIdx.x << 2) + (threadIdx.x >> 6);
  int l = threadIdx.x & 63;
  int b = row >> 10;
  const float4* cr = (const float4*)(cost + (size_t)row * TT);
  const float4* vb = (const float4*)(v + (size_t)b * TT);
  float s[16], m = -3.0e38f;
  #pragma unroll
  for (int i = 0; i < 4; ++i) {
    float4 c4 = cr[l + (i << 6)];
    float4 v4 = vb[l + (i << 6)];
    s[4*i+0] = (v4.x - c4.x) * INV_EPS;
    s[4*i+1] = (v4.y - c4.y) * INV_EPS;
    s[4*i+2] = (v4.z - c4.z) * INV_EPS;
    s[4*i+3] = (v4.w - c4.w) * INV_EPS;
    m = fmaxf(m, fmaxf(fmaxf(s[4*i+0], s[4*i+1]), fmaxf(s[4*i+2], s[4*i+3])));
  }
  m = wave_max64(m);
  float sum = 0.f;
  #pragma unroll
  for (int i = 0; i < 16; ++i) sum += expf(s[i] - m);
  sum = wave_sum64(sum);
  if (l == 0) u[row] = -EPS * (m + logf(sum));
}

// ---------------- v update ----------------
__global__ __launch_bounds__(256) void v_kernel(
    const float* __restrict__ cost, const float* __restrict__ costT, int useT,
    const float* __restrict__ filter, const float* __restrict__ u, float* __restrict__ v)
{
  int row = (blockIdx.x << 2) + (threadIdx.x >> 6);
  int l = threadIdx.x & 63;
  int b = row >> 10;
  int t = row & 1023;
  const float4* ub = (const float4*)(u + (size_t)b * QQ);
  bool filt = (filter[row] <= 0.f);   // wave-uniform; skip the 4KB read entirely
  float s[16], m = -3.0e38f;
  if (filt) {
    #pragma unroll
    for (int i = 0; i < 4; ++i) {
      float4 u4 = ub[l + (i << 6)];
      s[4*i+0] = (u4.x - FCONST) * INV_EPS;
      s[4*i+1] = (u4.y - FCONST) * INV_EPS;
      s[4*i+2] = (u4.z - FCONST) * INV_EPS;
      s[4*i+3] = (u4.w - FCONST) * INV_EPS;
      m = fmaxf(m, fmaxf(fmaxf(s[4*i+0], s[4*i+1]), fmaxf(s[4*i+2], s[4*i+3])));
    }
  } else if (useT) {
    const float4* cr = (const float4*)(costT + (size_t)row * QQ);
    #pragma unroll
    for (int i = 0; i < 4; ++i) {
      float4 u4 = ub[l + (i << 6)];
      float4 c4 = cr[l + (i << 6)];
      s[4*i+0] = (u4.x - c4.x) * INV_EPS;
      s[4*i+1] = (u4.y - c4.y) * INV_EPS;
      s[4*i+2] = (u4.z - c4.z) * INV_EPS;
      s[4*i+3] = (u4.w - c4.w) * INV_EPS;
      m = fmaxf(m, fmaxf(fmaxf(s[4*i+0], s[4*i+1]), fmaxf(s[4*i+2], s[4*i+3])));
    }
  } else {
    const float* cr = cost + (size_t)b*QQ*TT + t;
    #pragma unroll
    for (int i = 0; i < 4; ++i) {
      float4 u4 = ub[l + (i << 6)];
      int q = (l + (i << 6)) << 2;
      float c0 = cr[(size_t)(q+0) * TT];
      float c1 = cr[(size_t)(q+1) * TT];
      float c2 = cr[(size_t)(q+2) * TT];
      float c3 = cr[(size_t)(q+3) * TT];
      s[4*i+0] = (u4.x - c0) * INV_EPS;
      s[4*i+1] = (u4.y - c1) * INV_EPS;
      s[4*i+2] = (u4.z - c2) * INV_EPS;
      s[4*i+3] = (u4.w - c3) * INV_EPS;
      m = fmaxf(m, fmaxf(fmaxf(s[4*i+0], s[4*i+1]), fmaxf(s[4*i+2], s[4*i+3])));
    }
  }
  m = wave_max64(m);
  float sum = 0.f;
  #pragma unroll
  for (int i = 0; i < 16; ++i) sum += expf(s[i] - m);
  sum = wave_sum64(sum);
  if (l == 0) v[row] = -EPS * (m + logf(sum));
}

// ---------------- final: P in-place, argmax ----------------
__global__ __launch_bounds__(256) void p_kernel(
    float* __restrict__ P, const float* __restrict__ u, const float* __restrict__ v,
    float* __restrict__ idxOut)
{
  int row = (blockIdx.x << 2) + (threadIdx.x >> 6);
  int l = threadIdx.x & 63;
  int b = row >> 10;
  float4* cr = (float4*)(P + (size_t)row * TT);
  const float4* vb = (const float4*)(v + (size_t)b * TT);
  float uu = u[row];
  float bestp = -1.f; int bestt = 0;
  #pragma unroll
  for (int i = 0; i < 4; ++i) {
    float4 c4 = cr[l + (i << 6)];
    float4 v4 = vb[l + (i << 6)];
    int t0 = (l + (i << 6)) << 2;
    float4 p4;
    p4.x = expf((uu + v4.x - c4.x) * INV_EPS);
    p4.y = expf((uu + v4.y - c4.y) * INV_EPS);
    p4.z = expf((uu + v4.z - c4.z) * INV_EPS);
    p4.w = expf((uu + v4.w - c4.w) * INV_EPS);
    if (p4.x > bestp) { bestp = p4.x; bestt = t0 + 0; }
    if (p4.y > bestp) { bestp = p4.y; bestt = t0 + 1; }
    if (p4.z > bestp) { bestp = p4.z; bestt = t0 + 2; }
    if (p4.w > bestp) { bestp = p4.w; bestt = t0 + 3; }
    cr[l + (i << 6)] = p4;
  }
  #pragma unroll
  for (int o = 1; o < 64; o <<= 1) {
    float op = __shfl_xor(bestp, o, 64);
    int   ot = __shfl_xor(bestt, o, 64);
    if (op > bestp || (op == bestp && ot < bestt)) { bestp = op; bestt = ot; }
  }
  if (l == 0) idxOut[row] = (float)bestt;
}

extern "C" void kernel_launch(void* const* d_in, const int* in_sizes, int n_in,
                              void* d_out, int out_size, void* d_ws, size_t ws_size,
                              hipStream_t stream) {
  const float* preds   = (const float*)d_in[0];
  const float* targets = (const float*)d_in[1];
  const float* filter  = (const float*)d_in[2];
  float* out = (float*)d_out;
  float* idxOut = out;
  float* P = out + (size_t)BB*QQ;   // cost lives here until p_kernel

  const size_t F16A  = (size_t)BB*QQ*DD;            // elems per f16 array
  const size_t f16tot = 4 * F16A * sizeof(f16);     // 33.55 MB
  const size_t smallb = (size_t)4 * 16384 * sizeof(float); // x2,y2,u,v
  const size_t costTB = (size_t)BB * QQ * TT * sizeof(float);

  char* p = (char*)d_ws;
  int useF16 = ws_size >= f16tot + smallb;
  f16 *Ahi, *Alo, *Bhi, *Blo;
  float *x2, *y2, *u, *v, *costT;
  int useT;
  if (useF16) {
    Ahi = (f16*)p; Alo = Ahi + F16A; Bhi = Alo + F16A; Blo = Bhi + F16A;
    x2 = (float*)(p + f16tot); y2 = x2 + 16384; u = y2 + 16384; v = u + 16384;
    useT = ws_size >= f16tot + smallb + costTB;
    costT = (float*)(p + f16tot + smallb);
  } else {
    Ahi = Alo = Bhi = Blo = nullptr;
    x2 = (float*)p; y2 = x2 + 16384; u = y2 + 16384; v = u + 16384;
    useT = ws_size >= smallb + costTB;
    costT = (float*)(p + smallb);
  }

  // zero u,v (initial potentials)
  hipMemsetAsync(u, 0, (size_t)2 * 16384 * sizeof(float), stream);

  dim3 cg(TT/128, QQ/128, BB);
  if (useF16) {
    cvt_kernel<<<BB*(QQ+TT)/4, 256, 0, stream>>>(preds, targets, Ahi, Alo, Bhi, Blo, x2, y2);
    cost_mfma_kernel<<<cg, 256, 0, stream>>>(Ahi, Alo, Bhi, Blo, x2, y2, filter, P, costT, useT);
  } else {
    norms_kernel<<<BB*(QQ+TT), 64, 0, stream>>>(preds, targets, x2, y2);
    cost_fp32_kernel<<<cg, 256, 0, stream>>>(preds, targets, x2, y2, filter, P, costT, useT);
  }
  int rows_q = BB*QQ/4, rows_t = BB*TT/4;
  for (int it = 0; it < SINK_ITERS; ++it) {
    u_kernel<<<rows_q, 256, 0, stream>>>(P, v, u);
    v_kernel<<<rows_t, 256, 0, stream>>>(P, costT, useT, filter, u, v);
  }
  p_kernel<<<rows_q, 256, 0, stream>>>(P, u, v, idxOut);
}

// Round 4
// 263.615 us; speedup vs baseline: 1.5492x; 1.0885x over previous
//
#include <hip/hip_runtime.h>
#include <math.h>

#define BB 16
#define QQ 1024
#define TT 1024
#define DD 256
#define EPS 0.1f
#define SINK_ITERS 5
// FC replaces 2*max(cost); it cancels algebraically (filtered col: v_t = FC - lse;
// consumers subtract it back). Needs FC >> max(cost)+2; max cost ~40.
#define FCONST 128.0f
#define K2 14.426950408889634f        // (1/eps) * log2(e)
#define EPSLN2 0.069314718055994531f  // eps * ln(2)

typedef _Float16 f16;
typedef _Float16 f16x4 __attribute__((ext_vector_type(4)));
typedef _Float16 f16x8 __attribute__((ext_vector_type(8)));
typedef float f32x4 __attribute__((ext_vector_type(4)));

__device__ __forceinline__ float fast_exp2(float x) {
#if __has_builtin(__builtin_amdgcn_exp2f)
  return __builtin_amdgcn_exp2f(x);
#else
  return exp2f(x);
#endif
}
__device__ __forceinline__ float fast_log2(float x) {
#if __has_builtin(__builtin_amdgcn_logf)
  return __builtin_amdgcn_logf(x);
#else
  return log2f(x);
#endif
}

// ---------------- cvt: fp32 -> (hi,lo) f16 split + fused row norms ----------------
__global__ __launch_bounds__(256) void cvt_kernel(
    const float* __restrict__ preds, const float* __restrict__ targets,
    f16* __restrict__ Ahi, f16* __restrict__ Alo,
    f16* __restrict__ Bhi, f16* __restrict__ Blo,
    float* __restrict__ x2, float* __restrict__ y2)
{
  int w = threadIdx.x >> 6, l = threadIdx.x & 63;
  int row = blockIdx.x * 4 + w;
  const float* src; f16 *hi, *lo; float* nrm;
  if (row < BB*QQ) {
    src = preds + (size_t)row * DD;
    hi = Ahi + (size_t)row * DD; lo = Alo + (size_t)row * DD; nrm = x2 + row;
  } else {
    int r = row - BB*QQ;
    src = targets + (size_t)r * DD;
    hi = Bhi + (size_t)r * DD; lo = Blo + (size_t)r * DD; nrm = y2 + r;
  }
  float4 v = ((const float4*)src)[l];
  f16x4 h, lw;
  h.x = (f16)v.x; h.y = (f16)v.y; h.z = (f16)v.z; h.w = (f16)v.w;
  lw.x = (f16)(v.x - (float)h.x); lw.y = (f16)(v.y - (float)h.y);
  lw.z = (f16)(v.z - (float)h.z); lw.w = (f16)(v.w - (float)h.w);
  *(f16x4*)(hi + l*4) = h;
  *(f16x4*)(lo + l*4) = lw;
  float s = v.x*v.x + v.y*v.y + v.z*v.z + v.w*v.w;
  #pragma unroll
  for (int o = 32; o; o >>= 1) s += __shfl_down(s, o, 64);
  if (l == 0) *nrm = s;
}

// ---------------- MFMA cost kernel: 128x128 tile, 64x64/wave, 16x16x32 f16 ----------------
__global__ __launch_bounds__(256) void cost_mfma_kernel(
    const f16* __restrict__ Ahi, const f16* __restrict__ Alo,
    const f16* __restrict__ Bhi, const f16* __restrict__ Blo,
    const float* __restrict__ x2, const float* __restrict__ y2,
    const float* __restrict__ filter,
    float* __restrict__ cost, float* __restrict__ costT, int useT)
{
  __shared__ f16 sA[2][128*32];
  __shared__ f16 sB[2][128*32];
  int b = blockIdx.z;
  int q0 = blockIdx.y * 128, t0 = blockIdx.x * 128;
  int tid = threadIdx.x, w = tid >> 6, l = tid & 63;
  int rq = (w >> 1) * 64, rt = (w & 1) * 64;
  int fr = l & 15, fg = l >> 4;
  const f16* pA[2] = { Ahi + ((size_t)b*QQ + q0) * DD, Alo + ((size_t)b*QQ + q0) * DD };
  const f16* pB[2] = { Bhi + ((size_t)b*TT + t0) * DD, Blo + ((size_t)b*TT + t0) * DD };
  f32x4 acc[4][4] = {};
  for (int k0 = 0; k0 < DD; k0 += 32) {
    __syncthreads();
#if __has_builtin(__builtin_amdgcn_global_load_lds)
    #pragma unroll
    for (int j = 0; j < 2; ++j) {
      int chunk = w*128 + j*64 + l;
      int row = chunk >> 2, kc = chunk & 3;
      size_t go = (size_t)row * DD + k0 + kc*8;
      int lb = (w*128 + j*64) * 8;
      #pragma unroll
      for (int h = 0; h < 2; ++h) {
        __builtin_amdgcn_global_load_lds(
            (const __attribute__((address_space(1))) void*)(pA[h] + go),
            (__attribute__((address_space(3))) void*)&sA[h][lb], 16, 0, 0);
        __builtin_amdgcn_global_load_lds(
            (const __attribute__((address_space(1))) void*)(pB[h] + go),
            (__attribute__((address_space(3))) void*)&sB[h][lb], 16, 0, 0);
      }
    }
#else
    #pragma unroll
    for (int j = 0; j < 2; ++j) {
      int chunk = w*128 + j*64 + l;
      int row = chunk >> 2, kc = chunk & 3;
      size_t go = (size_t)row * DD + k0 + kc*8;
      #pragma unroll
      for (int h = 0; h < 2; ++h) {
        *(f16x8*)&sA[h][chunk*8] = *(const f16x8*)(pA[h] + go);
        *(f16x8*)&sB[h][chunk*8] = *(const f16x8*)(pB[h] + go);
      }
    }
#endif
    __syncthreads();
    f16x8 ah[4], al[4], bh[4], bl[4];
    #pragma unroll
    for (int f = 0; f < 4; ++f) {
      int ao = (rq + f*16 + fr)*32 + fg*8;
      ah[f] = *(const f16x8*)&sA[0][ao];
      al[f] = *(const f16x8*)&sA[1][ao];
      int bo = (rt + f*16 + fr)*32 + fg*8;
      bh[f] = *(const f16x8*)&sB[0][bo];
      bl[f] = *(const f16x8*)&sB[1][bo];
    }
    #pragma unroll
    for (int fm = 0; fm < 4; ++fm)
      #pragma unroll
      for (int fn = 0; fn < 4; ++fn) {
        acc[fm][fn] = __builtin_amdgcn_mfma_f32_16x16x32_f16(ah[fm], bh[fn], acc[fm][fn], 0, 0, 0);
        acc[fm][fn] = __builtin_amdgcn_mfma_f32_16x16x32_f16(ah[fm], bl[fn], acc[fm][fn], 0, 0, 0);
        acc[fm][fn] = __builtin_amdgcn_mfma_f32_16x16x32_f16(al[fm], bh[fn], acc[fm][fn], 0, 0, 0);
      }
  }
  float xv[16];
  #pragma unroll
  for (int fm = 0; fm < 4; ++fm)
    #pragma unroll
    for (int r = 0; r < 4; ++r)
      xv[fm*4+r] = x2[(size_t)b*QQ + q0 + rq + fm*16 + fg*4 + r];
  float yv[4], fv[4];
  #pragma unroll
  for (int fn = 0; fn < 4; ++fn) {
    int t = t0 + rt + fn*16 + fr;
    yv[fn] = y2[(size_t)b*TT + t];
    fv[fn] = filter[(size_t)b*TT + t];
  }
  #pragma unroll
  for (int fm = 0; fm < 4; ++fm) {
    #pragma unroll
    for (int fn = 0; fn < 4; ++fn) {
      int t = t0 + rt + fn*16 + fr;
      float cvr[4];
      #pragma unroll
      for (int r = 0; r < 4; ++r) {
        float c2 = xv[fm*4+r] + yv[fn] - 2.0f*acc[fm][fn][r];
        float c = sqrtf(fmaxf(c2, 0.f));
        if (fv[fn] <= 0.f) c = FCONST;
        cvr[r] = c;
        int q = q0 + rq + fm*16 + fg*4 + r;
        cost[((size_t)b*QQ + q)*TT + t] = c;
      }
      // filtered columns of costT are never read by v_kernel -> skip the write
      if (useT && fv[fn] > 0.f) {
        float* dst = costT + ((size_t)b*TT + t)*QQ + q0 + rq + fm*16 + fg*4;
        *(float4*)dst = make_float4(cvr[0], cvr[1], cvr[2], cvr[3]);
      }
    }
  }
}

// ---------------- fp32 fallback ----------------
__global__ __launch_bounds__(64) void norms_kernel(
    const float* __restrict__ preds, const float* __restrict__ targets,
    float* __restrict__ x2, float* __restrict__ y2)
{
  int row = blockIdx.x;
  const float* src; float* dst;
  if (row < BB*QQ) { src = preds + (size_t)row * DD; dst = x2 + row; }
  else { int r = row - BB*QQ; src = targets + (size_t)r * DD; dst = y2 + r; }
  float4 v = ((const float4*)src)[threadIdx.x];
  float s = v.x*v.x + v.y*v.y + v.z*v.z + v.w*v.w;
  #pragma unroll
  for (int o = 32; o; o >>= 1) s += __shfl_down(s, o, 64);
  if (threadIdx.x == 0) *dst = s;
}

#define LDSTR 132
__global__ __launch_bounds__(256) void cost_fp32_kernel(
    const float* __restrict__ preds, const float* __restrict__ targets,
    const float* __restrict__ x2, const float* __restrict__ y2,
    const float* __restrict__ filter,
    float* __restrict__ cost, float* __restrict__ costT, int useT)
{
  __shared__ float As[16*LDSTR];
  __shared__ float Bs[16*LDSTR];
  int b  = blockIdx.z;
  int q0 = blockIdx.y * 128;
  int t0 = blockIdx.x * 128;
  const float* Ab = preds   + ((size_t)b*QQ + q0) * DD;
  const float* Bb = targets + ((size_t)b*TT + t0) * DD;
  int tid = threadIdx.x;
  int srow = tid >> 2, sq = (tid & 3) << 2;
  int w = tid >> 6, l = tid & 63;
  int rq = ((w >> 1) << 6) + ((l >> 3) << 3);
  int rt = ((w & 1) << 6) + ((l & 7) << 3);
  float acc[8][8] = {};
  for (int k0 = 0; k0 < DD; k0 += 16) {
    float4 a0 = *(const float4*)(Ab + (size_t)srow*DD + k0 + sq);
    float4 a1 = *(const float4*)(Ab + (size_t)(srow+64)*DD + k0 + sq);
    float4 b0 = *(const float4*)(Bb + (size_t)srow*DD + k0 + sq);
    float4 b1 = *(const float4*)(Bb + (size_t)(srow+64)*DD + k0 + sq);
    __syncthreads();
    As[(sq+0)*LDSTR + srow] = a0.x; As[(sq+1)*LDSTR + srow] = a0.y;
    As[(sq+2)*LDSTR + srow] = a0.z; As[(sq+3)*LDSTR + srow] = a0.w;
    As[(sq+0)*LDSTR + srow+64] = a1.x; As[(sq+1)*LDSTR + srow+64] = a1.y;
    As[(sq+2)*LDSTR + srow+64] = a1.z; As[(sq+3)*LDSTR + srow+64] = a1.w;
    Bs[(sq+0)*LDSTR + srow] = b0.x; Bs[(sq+1)*LDSTR + srow] = b0.y;
    Bs[(sq+2)*LDSTR + srow] = b0.z; Bs[(sq+3)*LDSTR + srow] = b0.w;
    Bs[(sq+0)*LDSTR + srow+64] = b1.x; Bs[(sq+1)*LDSTR + srow+64] = b1.y;
    Bs[(sq+2)*LDSTR + srow+64] = b1.z; Bs[(sq+3)*LDSTR + srow+64] = b1.w;
    __syncthreads();
    #pragma unroll
    for (int k = 0; k < 16; ++k) {
      float4 af0 = *(const float4*)&As[k*LDSTR + rq];
      float4 af1 = *(const float4*)&As[k*LDSTR + rq + 4];
      float4 bf0 = *(const float4*)&Bs[k*LDSTR + rt];
      float4 bf1 = *(const float4*)&Bs[k*LDSTR + rt + 4];
      float aa[8] = {af0.x,af0.y,af0.z,af0.w,af1.x,af1.y,af1.z,af1.w};
      float bb[8] = {bf0.x,bf0.y,bf0.z,bf0.w,bf1.x,bf1.y,bf1.z,bf1.w};
      #pragma unroll
      for (int i = 0; i < 8; ++i)
        #pragma unroll
        for (int j = 0; j < 8; ++j)
          acc[i][j] = fmaf(aa[i], bb[j], acc[i][j]);
    }
  }
  float xq[8], yt[8], fvv[8];
  #pragma unroll
  for (int i = 0; i < 8; ++i) xq[i] = x2[(size_t)b*QQ + q0 + rq + i];
  #pragma unroll
  for (int j = 0; j < 8; ++j) {
    yt[j] = y2[(size_t)b*TT + t0 + rt + j];
    fvv[j] = filter[(size_t)b*TT + t0 + rt + j];
  }
  float cv[8][8];
  #pragma unroll
  for (int i = 0; i < 8; ++i)
    #pragma unroll
    for (int j = 0; j < 8; ++j) {
      float c2 = xq[i] + yt[j] - 2.f*acc[i][j];
      float c = sqrtf(fmaxf(c2, 0.f));
      if (fvv[j] <= 0.f) c = FCONST;
      cv[i][j] = c;
    }
  #pragma unroll
  for (int i = 0; i < 8; ++i) {
    float* dst = cost + ((size_t)b*QQ + q0 + rq + i) * TT + t0 + rt;
    *(float4*)dst       = make_float4(cv[i][0], cv[i][1], cv[i][2], cv[i][3]);
    *(float4*)(dst + 4) = make_float4(cv[i][4], cv[i][5], cv[i][6], cv[i][7]);
  }
  if (useT) {
    #pragma unroll
    for (int j = 0; j < 8; ++j) {
      if (fvv[j] <= 0.f) continue;
      float* dst = costT + ((size_t)b*TT + t0 + rt + j) * QQ + q0 + rq;
      *(float4*)dst       = make_float4(cv[0][j], cv[1][j], cv[2][j], cv[3][j]);
      *(float4*)(dst + 4) = make_float4(cv[4][j], cv[5][j], cv[6][j], cv[7][j]);
    }
  }
}

// ---------------- wave reductions ----------------
__device__ __forceinline__ float wave_max64(float v) {
  #pragma unroll
  for (int o = 1; o < 64; o <<= 1) v = fmaxf(v, __shfl_xor(v, o, 64));
  return v;
}
__device__ __forceinline__ float wave_sum64(float v) {
  #pragma unroll
  for (int o = 1; o < 64; o <<= 1) v += __shfl_xor(v, o, 64);
  return v;
}

// ---------------- u update: 2 rows per wave, base-2 lse ----------------
__global__ __launch_bounds__(256) void u_kernel(
    const float* __restrict__ cost, const float* __restrict__ v, float* __restrict__ u)
{
  int w = threadIdx.x >> 6, l = threadIdx.x & 63;
  int row = blockIdx.x * 8 + w * 2;
  int b = row >> 10;
  const float4* c0 = (const float4*)(cost + (size_t)row * TT);
  const float4* c1 = c0 + TT/4;
  const float4* vb = (const float4*)(v + (size_t)b * TT);
  float s0[16], s1[16], m0 = -3.0e38f, m1 = -3.0e38f;
  #pragma unroll
  for (int i = 0; i < 4; ++i) {
    float4 v4 = vb[l + (i << 6)];
    float4 a4 = c0[l + (i << 6)];
    float4 b4 = c1[l + (i << 6)];
    s0[4*i+0] = (v4.x - a4.x) * K2; s0[4*i+1] = (v4.y - a4.y) * K2;
    s0[4*i+2] = (v4.z - a4.z) * K2; s0[4*i+3] = (v4.w - a4.w) * K2;
    s1[4*i+0] = (v4.x - b4.x) * K2; s1[4*i+1] = (v4.y - b4.y) * K2;
    s1[4*i+2] = (v4.z - b4.z) * K2; s1[4*i+3] = (v4.w - b4.w) * K2;
    m0 = fmaxf(m0, fmaxf(fmaxf(s0[4*i+0], s0[4*i+1]), fmaxf(s0[4*i+2], s0[4*i+3])));
    m1 = fmaxf(m1, fmaxf(fmaxf(s1[4*i+0], s1[4*i+1]), fmaxf(s1[4*i+2], s1[4*i+3])));
  }
  m0 = wave_max64(m0); m1 = wave_max64(m1);
  float q0 = 0.f, q1 = 0.f;
  #pragma unroll
  for (int i = 0; i < 16; ++i) { q0 += fast_exp2(s0[i] - m0); q1 += fast_exp2(s1[i] - m1); }
  q0 = wave_sum64(q0); q1 = wave_sum64(q1);
  if (l == 0) {
    u[row]   = -EPSLN2 * (m0 + fast_log2(q0));
    u[row+1] = -EPSLN2 * (m1 + fast_log2(q1));
  }
}

// ---------------- v update: 2 columns per wave ----------------
__global__ __launch_bounds__(256) void v_kernel(
    const float* __restrict__ cost, const float* __restrict__ costT, int useT,
    const float* __restrict__ filter, const float* __restrict__ u, float* __restrict__ v)
{
  int w = threadIdx.x >> 6, l = threadIdx.x & 63;
  int row = blockIdx.x * 8 + w * 2;
  int b = row >> 10, t = row & 1023;
  const float4* ub = (const float4*)(u + (size_t)b * QQ);
  bool f0 = (filter[row]   <= 0.f);
  bool f1 = (filter[row+1] <= 0.f);
  float4 uw[4];
  #pragma unroll
  for (int i = 0; i < 4; ++i) uw[i] = ub[l + (i << 6)];
  float s0[16], s1[16], m0 = -3.0e38f, m1 = -3.0e38f;
  if (f0) {
    #pragma unroll
    for (int i = 0; i < 4; ++i) {
      s0[4*i+0] = (uw[i].x - FCONST) * K2; s0[4*i+1] = (uw[i].y - FCONST) * K2;
      s0[4*i+2] = (uw[i].z - FCONST) * K2; s0[4*i+3] = (uw[i].w - FCONST) * K2;
    }
  } else if (useT) {
    const float4* cr = (const float4*)(costT + (size_t)row * QQ);
    #pragma unroll
    for (int i = 0; i < 4; ++i) {
      float4 c4 = cr[l + (i << 6)];
      s0[4*i+0] = (uw[i].x - c4.x) * K2; s0[4*i+1] = (uw[i].y - c4.y) * K2;
      s0[4*i+2] = (uw[i].z - c4.z) * K2; s0[4*i+3] = (uw[i].w - c4.w) * K2;
    }
  } else {
    const float* cr = cost + (size_t)b*QQ*TT + t;
    #pragma unroll
    for (int i = 0; i < 4; ++i) {
      int q = (l + (i << 6)) << 2;
      s0[4*i+0] = (uw[i].x - cr[(size_t)(q+0)*TT]) * K2;
      s0[4*i+1] = (uw[i].y - cr[(size_t)(q+1)*TT]) * K2;
      s0[4*i+2] = (uw[i].z - cr[(size_t)(q+2)*TT]) * K2;
      s0[4*i+3] = (uw[i].w - cr[(size_t)(q+3)*TT]) * K2;
    }
  }
  if (f1) {
    #pragma unroll
    for (int i = 0; i < 4; ++i) {
      s1[4*i+0] = (uw[i].x - FCONST) * K2; s1[4*i+1] = (uw[i].y - FCONST) * K2;
      s1[4*i+2] = (uw[i].z - FCONST) * K2; s1[4*i+3] = (uw[i].w - FCONST) * K2;
    }
  } else if (useT) {
    const float4* cr = (const float4*)(costT + (size_t)(row+1) * QQ);
    #pragma unroll
    for (int i = 0; i < 4; ++i) {
      float4 c4 = cr[l + (i << 6)];
      s1[4*i+0] = (uw[i].x - c4.x) * K2; s1[4*i+1] = (uw[i].y - c4.y) * K2;
      s1[4*i+2] = (uw[i].z - c4.z) * K2; s1[4*i+3] = (uw[i].w - c4.w) * K2;
    }
  } else {
    const float* cr = cost + (size_t)b*QQ*TT + t + 1;
    #pragma unroll
    for (int i = 0; i < 4; ++i) {
      int q = (l + (i << 6)) << 2;
      s1[4*i+0] = (uw[i].x - cr[(size_t)(q+0)*TT]) * K2;
      s1[4*i+1] = (uw[i].y - cr[(size_t)(q+1)*TT]) * K2;
      s1[4*i+2] = (uw[i].z - cr[(size_t)(q+2)*TT]) * K2;
      s1[4*i+3] = (uw[i].w - cr[(size_t)(q+3)*TT]) * K2;
    }
  }
  #pragma unroll
  for (int i = 0; i < 16; ++i) { m0 = fmaxf(m0, s0[i]); m1 = fmaxf(m1, s1[i]); }
  m0 = wave_max64(m0); m1 = wave_max64(m1);
  float q0 = 0.f, q1 = 0.f;
  #pragma unroll
  for (int i = 0; i < 16; ++i) { q0 += fast_exp2(s0[i] - m0); q1 += fast_exp2(s1[i] - m1); }
  q0 = wave_sum64(q0); q1 = wave_sum64(q1);
  if (l == 0) {
    v[row]   = -EPSLN2 * (m0 + fast_log2(q0));
    v[row+1] = -EPSLN2 * (m1 + fast_log2(q1));
  }
}

// ---------------- final: P in-place, argmax; 2 rows per wave ----------------
__global__ __launch_bounds__(256) void p_kernel(
    float* __restrict__ P, const float* __restrict__ u, const float* __restrict__ v,
    float* __restrict__ idxOut)
{
  int w = threadIdx.x >> 6, l = threadIdx.x & 63;
  int row = blockIdx.x * 8 + w * 2;
  int b = row >> 10;
  float4* c0 = (float4*)(P + (size_t)row * TT);
  float4* c1 = c0 + TT/4;
  const float4* vb = (const float4*)(v + (size_t)b * TT);
  float u0 = u[row], u1 = u[row+1];
  float bp0 = -1.f, bp1 = -1.f; int bt0 = 0, bt1 = 0;
  #pragma unroll
  for (int i = 0; i < 4; ++i) {
    float4 v4 = vb[l + (i << 6)];
    float4 a4 = c0[l + (i << 6)];
    float4 b4 = c1[l + (i << 6)];
    int t0 = (l + (i << 6)) << 2;
    float4 p0, p1;
    p0.x = fast_exp2((u0 + v4.x - a4.x) * K2);
    p0.y = fast_exp2((u0 + v4.y - a4.y) * K2);
    p0.z = fast_exp2((u0 + v4.z - a4.z) * K2);
    p0.w = fast_exp2((u0 + v4.w - a4.w) * K2);
    p1.x = fast_exp2((u1 + v4.x - b4.x) * K2);
    p1.y = fast_exp2((u1 + v4.y - b4.y) * K2);
    p1.z = fast_exp2((u1 + v4.z - b4.z) * K2);
    p1.w = fast_exp2((u1 + v4.w - b4.w) * K2);
    if (p0.x > bp0) { bp0 = p0.x; bt0 = t0 + 0; }
    if (p0.y > bp0) { bp0 = p0.y; bt0 = t0 + 1; }
    if (p0.z > bp0) { bp0 = p0.z; bt0 = t0 + 2; }
    if (p0.w > bp0) { bp0 = p0.w; bt0 = t0 + 3; }
    if (p1.x > bp1) { bp1 = p1.x; bt1 = t0 + 0; }
    if (p1.y > bp1) { bp1 = p1.y; bt1 = t0 + 1; }
    if (p1.z > bp1) { bp1 = p1.z; bt1 = t0 + 2; }
    if (p1.w > bp1) { bp1 = p1.w; bt1 = t0 + 3; }
    c0[l + (i << 6)] = p0;
    c1[l + (i << 6)] = p1;
  }
  #pragma unroll
  for (int o = 1; o < 64; o <<= 1) {
    float op = __shfl_xor(bp0, o, 64);
    int   ot = __shfl_xor(bt0, o, 64);
    if (op > bp0 || (op == bp0 && ot < bt0)) { bp0 = op; bt0 = ot; }
    op = __shfl_xor(bp1, o, 64);
    ot = __shfl_xor(bt1, o, 64);
    if (op > bp1 || (op == bp1 && ot < bt1)) { bp1 = op; bt1 = ot; }
  }
  if (l == 0) { idxOut[row] = (float)bt0; idxOut[row+1] = (float)bt1; }
}

extern "C" void kernel_launch(void* const* d_in, const int* in_sizes, int n_in,
                              void* d_out, int out_size, void* d_ws, size_t ws_size,
                              hipStream_t stream) {
  const float* preds   = (const float*)d_in[0];
  const float* targets = (const float*)d_in[1];
  const float* filter  = (const float*)d_in[2];
  float* out = (float*)d_out;
  float* idxOut = out;
  float* P = out + (size_t)BB*QQ;   // cost lives here until p_kernel

  const size_t F16A  = (size_t)BB*QQ*DD;
  const size_t f16tot = 4 * F16A * sizeof(f16);
  const size_t smallb = (size_t)4 * 16384 * sizeof(float);
  const size_t costTB = (size_t)BB * QQ * TT * sizeof(float);

  char* p = (char*)d_ws;
  int useF16 = ws_size >= f16tot + smallb;
  f16 *Ahi, *Alo, *Bhi, *Blo;
  float *x2, *y2, *u, *v, *costT;
  int useT;
  if (useF16) {
    Ahi = (f16*)p; Alo = Ahi + F16A; Bhi = Alo + F16A; Blo = Bhi + F16A;
    x2 = (float*)(p + f16tot); y2 = x2 + 16384; u = y2 + 16384; v = u + 16384;
    useT = ws_size >= f16tot + smallb + costTB;
    costT = (float*)(p + f16tot + smallb);
  } else {
    Ahi = Alo = Bhi = Blo = nullptr;
    x2 = (float*)p; y2 = x2 + 16384; u = y2 + 16384; v = u + 16384;
    useT = ws_size >= smallb + costTB;
    costT = (float*)(p + smallb);
  }

  hipMemsetAsync(u, 0, (size_t)2 * 16384 * sizeof(float), stream);

  dim3 cg(TT/128, QQ/128, BB);
  if (useF16) {
    cvt_kernel<<<BB*(QQ+TT)/4, 256, 0, stream>>>(preds, targets, Ahi, Alo, Bhi, Blo, x2, y2);
    cost_mfma_kernel<<<cg, 256, 0, stream>>>(Ahi, Alo, Bhi, Blo, x2, y2, filter, P, costT, useT);
  } else {
    norms_kernel<<<BB*(QQ+TT), 64, 0, stream>>>(preds, targets, x2, y2);
    cost_fp32_kernel<<<cg, 256, 0, stream>>>(preds, targets, x2, y2, filter, P, costT, useT);
  }
  int blks = BB*QQ/8;   // 2 rows/wave * 4 waves
  for (int it = 0; it < SINK_ITERS; ++it) {
    u_kernel<<<blks, 256, 0, stream>>>(P, v, u);
    v_kernel<<<blks, 256, 0, stream>>>(P, costT, useT, filter, u, v);
  }
  p_kernel<<<blks, 256, 0, stream>>>(P, u, v, idxOut);
}